// Round 2
// 485.191 us; speedup vs baseline: 1.0007x; 1.0007x over previous
//
#include <hip/hip_runtime.h>

typedef __attribute__((ext_vector_type(8))) short bf16x8;
typedef __attribute__((ext_vector_type(8))) unsigned short u16x8;
typedef __attribute__((ext_vector_type(4))) unsigned short u16x4;
typedef __attribute__((ext_vector_type(4))) float f32x4;

#define HW      112
#define CH      64
#define PIX_IMG (HW*HW)            // 12544
#define N4TOT   (64*112*112*64/4)  // 12845056 float4s in x
#define NPIX_F  802816.0f          // 64*112*112

// ws layout (floats): [0..64) sum, [64..128) sumsq, [128..192) scale s,
// [192..256) bias b, [256..320) bias_out (= sum_tap,ci b*W).
// byte 1280: hv bf16[64] = bf16(-b/s)  (raw-x halo value -> x_bn == 0)
// byte 4096: W' bf16 [half][tap][qd][co][8]  (36864 ushorts, 73728 B), W' = s*W
// byte 4MB : raw bf16 x [n][h][w][ci]  (102,760,448 B) when ws_size permits
#define WS_HV_BYTE  1280
#define WS_W_BYTE   4096
#define WS_XBF_BYTE (4u<<20)

__device__ __forceinline__ unsigned short f2bf(float f) {
  unsigned u = __float_as_uint(f);
  u += 0x7FFFu + ((u >> 16) & 1u);   // round-to-nearest-even
  return (unsigned short)(u >> 16);
}

// ---------------- kernel 0: zero the stat accumulators ----------------
__global__ void zero_ws(float* __restrict__ ws) {
  ws[threadIdx.x] = 0.0f;   // 128 threads: sum[64], sumsq[64]
}

// ---------------- kernel 1: per-channel sum/sumsq (+ optional raw bf16 x) ----
// nt loads (x is read-once here) + nt stores (xbf not re-read until conv,
// working set >> L2) keep L2 clean.
template <bool WRITE_BF>
__global__ __launch_bounds__(256) void stats_kernel(const float* __restrict__ x,
                                                    float* __restrict__ ws,
                                                    unsigned short* __restrict__ xbf) {
  __shared__ float red[128];
  const int tid = threadIdx.x;
  if (tid < 128) red[tid] = 0.0f;
  __syncthreads();

  const f32x4* __restrict__ x4 = (const f32x4*)x;
  f32x4 s = {0.f, 0.f, 0.f, 0.f};
  f32x4 q = {0.f, 0.f, 0.f, 0.f};
  const int stride = gridDim.x * 256;
  #pragma unroll 4
  for (int i = blockIdx.x * 256 + tid; i < N4TOT; i += stride) {
    f32x4 v = __builtin_nontemporal_load(&x4[i]);
    s += v;
    q += v * v;
    if (WRITE_BF) {
      u16x4 o = {f2bf(v[0]), f2bf(v[1]), f2bf(v[2]), f2bf(v[3])};
      __builtin_nontemporal_store(o, (u16x4*)(xbf + 4 * i));
    }
  }
  // lanes l, l^16, l^32 share the same channel quad -> shuffle pre-reduce
  #pragma unroll
  for (int m = 16; m <= 32; m <<= 1) {
    #pragma unroll
    for (int j = 0; j < 4; ++j) {
      s[j] += __shfl_xor(s[j], m);
      q[j] += __shfl_xor(q[j], m);
    }
  }
  if ((tid & 63) < 16) {
    const int c0 = (tid & 15) * 4;
    #pragma unroll
    for (int j = 0; j < 4; ++j) {
      atomicAdd(&red[c0 + j], s[j]);
      atomicAdd(&red[64 + c0 + j], q[j]);
    }
  }
  __syncthreads();
  if (tid < 128) atomicAdd(&ws[tid], red[tid]);
}

// ---------------- kernel 2: scale/bias/halo + bias_out = sum b*W -------------
__global__ __launch_bounds__(256) void finalize_kernel(const float* __restrict__ beta,
                                                       const float* __restrict__ k,
                                                       float* __restrict__ ws) {
  __shared__ float sb[64];
  __shared__ float part[256];
  const int tid = threadIdx.x;
  if (tid < 64) {
    float mean = ws[tid] * (1.0f / NPIX_F);
    float var  = fmaxf(ws[64 + tid] * (1.0f / NPIX_F) - mean * mean, 0.0f);
    float sc = rsqrtf(var + 1e-5f);
    float b  = beta[tid] - mean * sc;
    ws[128 + tid] = sc;
    ws[192 + tid] = b;
    ((unsigned short*)((char*)ws + WS_HV_BYTE))[tid] = f2bf(-b / sc);
    sb[tid] = b;
  }
  __syncthreads();
  const int co = tid & 63, pt = tid >> 6;
  float a = 0.f;
  #pragma unroll 8
  for (int t = pt; t < 576; t += 4)          // t = tap*64 + ci
    a = fmaf(sb[t & 63], k[t * 64 + co], a);
  part[tid] = a;
  __syncthreads();
  if (tid < 64)
    ws[256 + tid] = part[tid] + part[64 + tid] + part[128 + tid] + part[192 + tid];
}

// ---------------- kernel 3: W' = s*W, layout [half][tap][qd][co][8] ----------
__global__ __launch_bounds__(256) void prep_w(const float* __restrict__ k,
                                              const float* __restrict__ ws,
                                              unsigned short* __restrict__ wsw) {
  const int oidx = blockIdx.x * 256 + threadIdx.x;  // 36864 total
  const int j  = oidx & 7;
  const int co = (oidx >> 3) & 63;
  const int qd = (oidx >> 9) & 3;
  const int t2 = oidx >> 11;          // 0..17
  const int tap = t2 % 9;
  const int h   = t2 / 9;
  const int ci  = h * 32 + qd * 8 + j;
  wsw[oidx] = f2bf(k[(tap * 64 + ci) * 64 + co] * ws[128 + ci]);
}

// ---------------- kernel 4: 3x3 conv, implicit GEMM, raw-bf16 staging --------
// Block: 448 threads (7 waves) = 4 output rows of one image.
// XCD swizzle: consecutive (n,h0) blocks -> same XCD so the 2 shared halo rows
//   between h0 and h0+4 hit that XCD's L2 (1792 = 8 * 224, bijective).
// LDS Xs: qd-plane layout [qd][row 6][px 114][8 ushorts] (16B px stride;
//   qd planes 10,944 B apart). 43,776 B.
// LDS Wd: FULL per-half W' slice staged once, LINEAR layout
//   [tap 9][qd 4][co 64][8] = 18,432 ushorts = 36,864 B. (Round-0's per-qd
//   bank stagger overflowed the 2048-ushort tap block -> staging collision;
//   removed — measured bank conflicts were only ~0.005% of cycle budget.)
// Barriers: 3/block (was 8). LDS total 80,640 B -> 2 blocks/CU.
// Compute: per half, xb ring-of-4 reuses row fragments across dh:
//   LDS reads/wave/half = 18 xb + 36 wa = 54 (was 72), 144 MFMA, no barriers.
// Output: non-temporal stores (write-once; keep L2 for xbf halo reuse).
template <bool USE_BF>
__global__ __launch_bounds__(448, 4) void conv_kernel(const float* __restrict__ x,
                                                      const unsigned short* __restrict__ xbf,
                                                      const unsigned short* __restrict__ wsw,
                                                      const float* __restrict__ ws,
                                                      float* __restrict__ out) {
  __shared__ unsigned short Xs[4 * 6 * 114 * 8];   // 21,888 ushorts = 43,776 B
  __shared__ unsigned short Wd[2304 * 8];          // 18,432 ushorts = 36,864 B
  const int tid = threadIdx.x;
  int bid = (int)blockIdx.x;
  bid = (bid & 7) * 224 + (bid >> 3);              // XCD-contiguous chunks
  const int n  = bid / 28;
  const int h0 = (bid % 28) * 4;

  const int lane = tid & 63;
  const int wv   = tid >> 6;    // 0..6 -> out w base = 16*wv
  const int qd   = lane >> 4;
  const int cc   = lane & 15;
  const int wvb  = wv * 16;

  const unsigned short* hv = (const unsigned short*)((const char*)ws + WS_HV_BYTE);

  // acc init = bias_out (covers the +b term for every tap; halo yields 0)
  f32x4 acc[4][4];
  {
    const float* bo = ws + 256;
    #pragma unroll
    for (int mt = 0; mt < 4; ++mt) {
      const f32x4 bv = *(const f32x4*)(bo + mt * 16 + qd * 4);
      #pragma unroll
      for (int r = 0; r < 4; ++r) acc[r][mt] = bv;
    }
  }

  for (int half = 0; half < 2; ++half) {
    // ---- stage Xs: rows h0-1..h0+4, px 0..113, ci' = half*32 .. +32 ----
    {
      u16x8 hv8[4];
      #pragma unroll
      for (int o = 0; o < 4; ++o) hv8[o] = *(const u16x8*)(hv + half * 32 + o * 8);
      auto stage = [&](int c) {
        const int o  = c & 3;         // qd plane
        const int pi = c >> 2;        // r*114 + p
        const int p  = pi % 114;
        const int r  = pi / 114;
        const int w  = p - 1;
        const int g  = h0 + r - 1;
        u16x8 v;
        if ((unsigned)w < 112u && (unsigned)g < 112u) {
          const int base = ((n * 112 + g) * 112 + w) * 64 + half * 32 + o * 8;
          if (USE_BF) {
            v = *(const u16x8*)(xbf + base);
          } else {
            const float* sp = x + base;
            const f32x4 a = *(const f32x4*)sp;
            const f32x4 b = *(const f32x4*)(sp + 4);
            v = (u16x8){f2bf(a[0]), f2bf(a[1]), f2bf(a[2]), f2bf(a[3]),
                        f2bf(b[0]), f2bf(b[1]), f2bf(b[2]), f2bf(b[3])};
          }
        } else {
          v = hv8[o];
        }
        *(u16x8*)(&Xs[o * 5472 + pi * 8]) = v;   // plane stride 6*114*8
      };
      #pragma unroll
      for (int kk = 0; kk < 6; ++kk) stage(kk * 448 + tid);
      if (tid < 48) stage(2688 + tid);
    }
    // ---- stage full-half Wd (linear, collision-free) ----
    {
      const unsigned short* wh = wsw + half * 18432;
      auto wstage = [&](int t) {    // t = ((dh*3+dw)*4+qd)*64 + co
        *(u16x8*)(&Wd[t * 8]) = *(const u16x8*)(wh + t * 8);
      };
      #pragma unroll
      for (int kk = 0; kk < 5; ++kk) wstage(kk * 448 + tid);
      if (tid < 64) wstage(2240 + tid);
    }
    __syncthreads();

    // ---- compute: all 9 taps, no internal barriers; xb ring-of-4 ----
    #pragma unroll
    for (int dw = 0; dw < 3; ++dw) {
      bf16x8 xb[4];
      #pragma unroll
      for (int rr = 0; rr < 4; ++rr)
        xb[rr] = *(const bf16x8*)(&Xs[qd * 5472 + (rr * 114 + wvb + dw + cc) * 8]);
      #pragma unroll
      for (int dh = 0; dh < 3; ++dh) {
        if (dh)   // replace oldest row with row dh+3 (indices fold at compile time)
          xb[(dh + 3) & 3] =
              *(const bf16x8*)(&Xs[qd * 5472 + ((dh + 3) * 114 + wvb + dw + cc) * 8]);
        #pragma unroll
        for (int mt = 0; mt < 4; ++mt) {
          const bf16x8 wa = *(const bf16x8*)(
              &Wd[(((dh * 3 + dw) * 4 + qd) * 64 + mt * 16 + cc) * 8]);
          #pragma unroll
          for (int r = 0; r < 4; ++r)
            acc[r][mt] = __builtin_amdgcn_mfma_f32_16x16x32_bf16(wa, xb[(dh + r) & 3],
                                                                 acc[r][mt], 0, 0, 0);
        }
      }
    }
    if (half == 0) __syncthreads();   // guards Xs/Wd restage; none needed after half1
  }

  // epilogue: lane holds px col = cc, co rows = mt*16 + qd*4 + 0..3
  #pragma unroll
  for (int r = 0; r < 4; ++r) {
    const int pix = n * PIX_IMG + (h0 + r) * 112 + wvb + cc;
    float* op = out + pix * 64 + qd * 4;
    #pragma unroll
    for (int mt = 0; mt < 4; ++mt)
      __builtin_nontemporal_store(acc[r][mt], (f32x4*)(op + mt * 16));
  }
}

extern "C" void kernel_launch(void* const* d_in, const int* in_sizes, int n_in,
                              void* d_out, int out_size, void* d_ws, size_t ws_size,
                              hipStream_t stream) {
  const float* x    = (const float*)d_in[0];
  const float* kern = (const float*)d_in[1];
  const float* beta = (const float*)d_in[2];
  float* out = (float*)d_out;
  float* ws  = (float*)d_ws;
  unsigned short* wsw = (unsigned short*)((char*)d_ws + WS_W_BYTE);
  unsigned short* xbf = (unsigned short*)((char*)d_ws + WS_XBF_BYTE);

  const bool use_bf = ws_size >= (size_t)WS_XBF_BYTE + 102760448ull;

  zero_ws<<<1, 128, 0, stream>>>(ws);
  if (use_bf) stats_kernel<true ><<<1024, 256, 0, stream>>>(x, ws, xbf);
  else        stats_kernel<false><<<1024, 256, 0, stream>>>(x, ws, xbf);
  finalize_kernel<<<1, 256, 0, stream>>>(beta, kern, ws);
  prep_w<<<144, 256, 0, stream>>>(kern, ws, wsw);
  if (use_bf) conv_kernel<true ><<<64 * 28, 448, 0, stream>>>(x, xbf, wsw, ws, out);
  else        conv_kernel<false><<<64 * 28, 448, 0, stream>>>(x, xbf, wsw, ws, out);
}